// Round 2
// baseline (9571.668 us; speedup 1.0000x reference)
//
#include <hip/hip_runtime.h>
#include <hip/hip_bf16.h>
#include <math.h>

#define N_TOK 2048
#define DMODEL 1024
#define HEADS 16
#define DK 64
#define DFF 4096
#define LAYERS 6

__device__ __forceinline__ float bf2f(unsigned short u) {
  union { unsigned int i; float f; } x; x.i = ((unsigned int)u) << 16; return x.f;
}

// Mixed-dtype loads: isbf=1 -> elements are bf16 (ushort), else fp32.
__device__ __forceinline__ float ldmix(const void* p, size_t i, bool isbf) {
  if (isbf) return bf2f(reinterpret_cast<const unsigned short*>(p)[i]);
  return reinterpret_cast<const float*>(p)[i];
}
__device__ __forceinline__ void ldmix4(const void* p, size_t i, bool isbf, float out[4]) {
  if (isbf) {
    ushort4 u = *reinterpret_cast<const ushort4*>(reinterpret_cast<const unsigned short*>(p) + i);
    out[0] = bf2f(u.x); out[1] = bf2f(u.y); out[2] = bf2f(u.z); out[3] = bf2f(u.w);
  } else {
    float4 f = *reinterpret_cast<const float4*>(reinterpret_cast<const float*>(p) + i);
    out[0] = f.x; out[1] = f.y; out[2] = f.z; out[3] = f.w;
  }
}

// ---------------- input dtype detector ----------------
// View emb as bf16 pairs. True bf16 data: |v| <= ~0.2. True fp32 data: the
// low-half views have uniform-random exponents -> max over 8192 blows past 1e3
// (or hits NaN/Inf). Writes flag=1 for bf16, 0 for fp32.
__global__ __launch_bounds__(256) void detect_kernel(const void* emb, int* flag) {
  __shared__ float red[256];
  int t = threadIdx.x;
  const unsigned short* u = reinterpret_cast<const unsigned short*>(emb);
  float mx = 0.f;
  for (int i = t; i < 8192; i += 256) {
    float v = fabsf(bf2f(u[i]));
    if (!isfinite(v)) v = 1e30f;
    mx = fmaxf(mx, v);
  }
  red[t] = mx;
  __syncthreads();
  for (int s = 128; s > 0; s >>= 1) {
    if (t < s) red[t] = fmaxf(red[t], red[t + s]);
    __syncthreads();
  }
  if (t == 0) flag[0] = (red[0] < 1000.0f) ? 1 : 0;
}

// ---------------- embedding + positional encoding ----------------
__global__ __launch_bounds__(256) void embed_pe_kernel(
    const int* __restrict__ X, const void* __restrict__ emb,
    float* __restrict__ h, const int* __restrict__ dtf)
{
  const bool isbf = (*dtf != 0);
  int n = blockIdx.x;
  int row = X[n];
  float pos = (float)(n + 1);
  #pragma unroll
  for (int i = 0; i < 4; i++) {
    int j = threadIdx.x + i * 256;
    int je = j & ~1;
    float f = expf((float)je * (-9.2103403719761836f / 1024.0f)); // exp(je/d * -ln 10000)
    float t = pos * f;
    float p = (j & 1) ? cosf(t) : sinf(t);
    h[(size_t)n * DMODEL + j] = ldmix(emb, (size_t)row * DMODEL + j, isbf) + p;
  }
}

// ---------------- generic fp32 GEMM: C = A(f32)[M,K] @ B(mix) + bias(mix) ----------------
// B/bias indexed at (boff + local), so host never advances typed pointers.
// BMODE 0: B row-major [K,N].  BMODE 1: B per-head [H][K][64].
// OPERM 0: C[m*N+c].           OPERM 1: C[((c>>6)*M + m)*64 + (c&63)].
template<int BMODE, int OPERM, int RELU>
__global__ __launch_bounds__(256) void gemm_kernel(
    const float* __restrict__ A, const void* __restrict__ B, size_t boff,
    const void* __restrict__ bias, size_t biasoff, float* __restrict__ C,
    int M, int N, int K, const int* __restrict__ dtf)
{
  const bool isbf = (*dtf != 0);
  __shared__ float As[16][68];
  __shared__ float Bs[16][68];
  int n0 = blockIdx.x * 64, m0 = blockIdx.y * 64;
  int t = threadIdx.x;
  int tx = t & 15, ty = t >> 4;
  float acc[4][4] = {};
  int amm = t >> 2, akk = (t & 3) * 4;   // A tile: 64 rows x 16 k
  int bkk = t >> 4, bnn = (t & 15) * 4;  // B tile: 16 k x 64 cols
  for (int k0 = 0; k0 < K; k0 += 16) {
    float4 av = *reinterpret_cast<const float4*>(A + (size_t)(m0 + amm) * K + k0 + akk);
    As[akk + 0][amm] = av.x; As[akk + 1][amm] = av.y;
    As[akk + 2][amm] = av.z; As[akk + 3][amm] = av.w;
    int krow = k0 + bkk;
    int cb = n0 + bnn;
    size_t bidx;
    if (BMODE == 0) bidx = (size_t)krow * N + cb;
    else            bidx = ((size_t)(cb >> 6) * K + krow) * 64 + (cb & 63);
    float bv[4];
    ldmix4(B, boff + bidx, isbf, bv);
    Bs[bkk][bnn + 0] = bv[0]; Bs[bkk][bnn + 1] = bv[1];
    Bs[bkk][bnn + 2] = bv[2]; Bs[bkk][bnn + 3] = bv[3];
    __syncthreads();
    #pragma unroll
    for (int kk = 0; kk < 16; kk++) {
      float4 a4 = *reinterpret_cast<const float4*>(&As[kk][ty * 4]);
      float4 b4 = *reinterpret_cast<const float4*>(&Bs[kk][tx * 4]);
      float a[4] = {a4.x, a4.y, a4.z, a4.w};
      float b[4] = {b4.x, b4.y, b4.z, b4.w};
      #pragma unroll
      for (int i = 0; i < 4; i++)
        #pragma unroll
        for (int j = 0; j < 4; j++)
          acc[i][j] += a[i] * b[j];
    }
    __syncthreads();
  }
  #pragma unroll
  for (int i = 0; i < 4; i++) {
    int m = m0 + ty * 4 + i;
    #pragma unroll
    for (int j = 0; j < 4; j++) {
      int c = n0 + tx * 4 + j;
      float v = acc[i][j] + ldmix(bias, biasoff + c, isbf);
      if (RELU) v = fmaxf(v, 0.0f);
      if (OPERM) C[((size_t)(c >> 6) * M + m) * 64 + (c & 63)] = v;
      else       C[(size_t)m * N + c] = v;
    }
  }
}

// ---------------- per-column (query-axis) logsumexp of S = Q K^T / 8 ----------------
__global__ __launch_bounds__(256) void colstats_kernel(
    const float* __restrict__ Q, const float* __restrict__ Km, float* __restrict__ cst)
{
  __shared__ float Ks[16][65];
  __shared__ float Qs[64][65];
  __shared__ float redM[256], redS[256];
  int h = blockIdx.y;
  int m0 = blockIdx.x * 16;
  int t = threadIdx.x;
  const float* Kh = Km + ((size_t)h * N_TOK + m0) * DK;
  for (int e = t; e < 16 * 64; e += 256) Ks[e >> 6][e & 63] = Kh[e];
  int m_loc = t & 15, ngrp = t >> 4;
  float vmax = -INFINITY, vsum = 0.f;
  const float* Qh = Q + (size_t)h * N_TOK * DK;
  for (int n0 = 0; n0 < N_TOK; n0 += 64) {
    __syncthreads();
    for (int e = t; e < 64 * 64; e += 256)
      Qs[e >> 6][e & 63] = Qh[(size_t)(n0 + (e >> 6)) * DK + (e & 63)];
    __syncthreads();
    #pragma unroll
    for (int r = 0; r < 4; r++) {
      int nn = ngrp * 4 + r;
      float dot = 0.f;
      #pragma unroll
      for (int kk = 0; kk < 64; kk++) dot += Qs[nn][kk] * Ks[m_loc][kk];
      dot *= 0.125f;
      if (dot > vmax) { vsum = vsum * expf(vmax - dot) + 1.0f; vmax = dot; }
      else vsum += expf(dot - vmax);
    }
  }
  redM[t] = vmax; redS[t] = vsum;
  __syncthreads();
  if (t < 16) {
    float M = -INFINITY, S = 0.f;
    for (int g = 0; g < 16; g++) {
      float m2 = redM[g * 16 + t], s2 = redS[g * 16 + t];
      if (m2 > M) { S = S * expf(M - m2) + s2; M = m2; }
      else S += s2 * expf(m2 - M);
    }
    cst[h * N_TOK + m0 + t] = M + logf(S);
  }
}

// ---------------- KtV[h] = K[h]^T V[h], cv[h][v] = sum_m cst[h][m] V[h][m][v] ----------------
__global__ __launch_bounds__(256) void ktv_kernel(
    const float* __restrict__ Km, const float* __restrict__ V, const float* __restrict__ cst,
    float* __restrict__ KtV, float* __restrict__ cv)
{
  __shared__ float Ks[64][65];
  __shared__ float Vs[64][65];
  __shared__ float cs[64];
  int h = blockIdx.x, t = threadIdx.x;
  int v = t & 63, kg = t >> 6;
  float acc[16] = {};
  float cacc = 0.f;
  for (int m0 = 0; m0 < N_TOK; m0 += 64) {
    __syncthreads();
    for (int e = t; e < 4096; e += 256) {
      int r = e >> 6, cl = e & 63;
      size_t gi = ((size_t)h * N_TOK + m0 + r) * DK + cl;
      Ks[r][cl] = Km[gi];
      Vs[r][cl] = V[gi];
    }
    if (t < 64) cs[t] = cst[h * N_TOK + m0 + t];
    __syncthreads();
    #pragma unroll 4
    for (int mm = 0; mm < 64; mm++) {
      float vv = Vs[mm][v];
      #pragma unroll
      for (int kk = 0; kk < 16; kk++) acc[kk] += Ks[mm][kg * 16 + kk] * vv;
      cacc += cs[mm] * vv;
    }
  }
  #pragma unroll
  for (int kk = 0; kk < 16; kk++)
    KtV[((size_t)h * 64 + kg * 16 + kk) * 64 + v] = acc[kk];
  if (kg == 0) cv[h * 64 + v] = cacc;
}

// ---------------- attn[n][h*64+v] = (1/8) Q[h][n][:]·KtV[h][:][v] − cv[h][v] ----------------
__global__ __launch_bounds__(256) void attn_kernel(
    const float* __restrict__ Q, const float* __restrict__ KtV, const float* __restrict__ cv,
    float* __restrict__ attn)
{
  __shared__ float Ws[64][65];
  __shared__ float Qs[64][65];
  __shared__ float cvs[64];
  int h = blockIdx.y, n0 = blockIdx.x * 64, t = threadIdx.x;
  for (int e = t; e < 4096; e += 256) Ws[e >> 6][e & 63] = KtV[(size_t)h * 4096 + e];
  for (int e = t; e < 4096; e += 256)
    Qs[e >> 6][e & 63] = Q[((size_t)h * N_TOK + n0) * DK + e];
  if (t < 64) cvs[t] = cv[h * 64 + t];
  __syncthreads();
  int nl = t >> 2, vg = t & 3;
  float acc[16] = {};
  #pragma unroll 8
  for (int kk = 0; kk < 64; kk++) {
    float qv = Qs[nl][kk];
    #pragma unroll
    for (int j = 0; j < 16; j++) acc[j] += qv * Ws[kk][vg * 16 + j];
  }
  #pragma unroll
  for (int j = 0; j < 16; j++) {
    int vv = vg * 16 + j;
    attn[(size_t)(n0 + nl) * DMODEL + h * 64 + vv] = 0.125f * acc[j] - cvs[vv];
  }
}

// ---------------- layernorm(a + r), unbiased std (ddof=1), per-element gain/bias ----------------
__global__ __launch_bounds__(256) void ln_kernel(
    const float* __restrict__ a, const float* __restrict__ r,
    const void* __restrict__ g, const void* __restrict__ be, size_t goff,
    float* __restrict__ out, void* __restrict__ outb, const int* __restrict__ dtf)
{
  const bool isbf = (*dtf != 0);
  __shared__ float red[4];
  int n = blockIdx.x, t = threadIdx.x;
  const float* ap = a + (size_t)n * DMODEL;
  const float* rp = r + (size_t)n * DMODEL;
  float x[4];
  float s = 0.f;
  #pragma unroll
  for (int i = 0; i < 4; i++) { x[i] = ap[t + i * 256] + rp[t + i * 256]; s += x[i]; }
  #pragma unroll
  for (int o = 32; o > 0; o >>= 1) s += __shfl_down(s, o, 64);
  int lane = t & 63, w = t >> 6;
  if (lane == 0) red[w] = s;
  __syncthreads();
  float mean = (red[0] + red[1] + red[2] + red[3]) * (1.0f / 1024.0f);
  __syncthreads();
  float vs = 0.f;
  #pragma unroll
  for (int i = 0; i < 4; i++) { float d = x[i] - mean; vs += d * d; }
  #pragma unroll
  for (int o = 32; o > 0; o >>= 1) vs += __shfl_down(vs, o, 64);
  if (lane == 0) red[w] = vs;
  __syncthreads();
  float var = (red[0] + red[1] + red[2] + red[3]) * (1.0f / 1023.0f);
  float rstd = 1.0f / sqrtf(var);
  #pragma unroll
  for (int i = 0; i < 4; i++) {
    int j = t + i * 256;
    size_t gi = (size_t)n * DMODEL + j;
    float o = ldmix(g, goff + gi, isbf) * rstd * (x[i] - mean) + ldmix(be, goff + gi, isbf);
    out[gi] = o;
    if (outb) {
      if (isbf) reinterpret_cast<__hip_bfloat16*>(outb)[gi] = __float2bfloat16(o);
      else      reinterpret_cast<float*>(outb)[gi] = o;
    }
  }
}

extern "C" void kernel_launch(void* const* d_in, const int* in_sizes, int n_in,
                              void* d_out, int out_size, void* d_ws, size_t ws_size,
                              hipStream_t stream) {
  const int* X = (const int*)d_in[0];
  const void* emb = d_in[1];
  const void* WQ  = d_in[2];
  const void* bQ  = d_in[3];
  const void* WK  = d_in[4];
  const void* bK  = d_in[5];
  const void* WV  = d_in[6];
  const void* bV  = d_in[7];
  const void* WO  = d_in[8];
  const void* bO  = d_in[9];
  const void* W1  = d_in[10];
  const void* b1  = d_in[11];
  const void* W2  = d_in[12];
  const void* b2  = d_in[13];
  const void* g1  = d_in[14];
  const void* be1 = d_in[15];
  const void* g2  = d_in[16];
  const void* be2 = d_in[17];

  const size_t NM = (size_t)N_TOK * DMODEL;  // 2,097,152
  float* ws = (float*)d_ws;
  // layout (floats), ~59 MB total:
  float* h    = ws;                 // [0, 2M)    residual
  float* h2   = h + NM;             // [2M, 4M)   post-LN1
  float* kbuf = h2 + NM;            // [4M, 6M)   K; later z (WO out); later rbuf (FFN2 out)
  float* q    = kbuf + NM;          // [6M, 8M)   Q; later head of mid
  float* vbuf = q + NM;             // [8M, 10M)  V; later part of mid
  float* e1   = vbuf + NM;          // [10M,12M)  attn concat; later part of mid
  float* e2   = e1 + NM;            // [12M,14M)  tail of mid
  float* mid  = q;                  // [6M, 14M)  FFN intermediate [N, DFF]
  float* attn = e1;
  float* z    = kbuf;               // K dead after ktv_kernel
  float* rbuf = kbuf;               // z dead after ln1
  float* cst  = e2 + NM;                    // [H][N]
  float* ktv  = cst + HEADS * N_TOK;        // [H][64][64]
  float* cv   = ktv + HEADS * 64 * 64;      // [H][64]
  int*   dtf  = (int*)(cv + HEADS * 64);    // dtype flag

  detect_kernel<<<1, 256, 0, stream>>>(emb, dtf);
  embed_pe_kernel<<<N_TOK, 256, 0, stream>>>(X, emb, h, dtf);

  for (int l = 0; l < LAYERS; l++) {
    const size_t oWq = (size_t)l * HEADS * DMODEL * DK;
    const size_t obq = (size_t)l * HEADS * DK;
    const size_t oWO = (size_t)l * DMODEL * DMODEL;
    const size_t obO = (size_t)l * DMODEL;
    const size_t oW1 = (size_t)l * DMODEL * DFF;
    const size_t ob1 = (size_t)l * DFF;
    const size_t oW2 = (size_t)l * DFF * DMODEL;
    const size_t ob2 = (size_t)l * DMODEL;
    const size_t oLN = (size_t)l * NM;

    // Q,K,V projections -> head-major [h][n][64]
    gemm_kernel<1, 1, 0><<<dim3(16, 32), 256, 0, stream>>>(h, WQ, oWq, bQ, obq, q,    N_TOK, DMODEL, DMODEL, dtf);
    gemm_kernel<1, 1, 0><<<dim3(16, 32), 256, 0, stream>>>(h, WK, oWq, bK, obq, kbuf, N_TOK, DMODEL, DMODEL, dtf);
    gemm_kernel<1, 1, 0><<<dim3(16, 32), 256, 0, stream>>>(h, WV, oWq, bV, obq, vbuf, N_TOK, DMODEL, DMODEL, dtf);
    // per-key logsumexp over the query axis (log_softmax axis=1)
    colstats_kernel<<<dim3(N_TOK / 16, HEADS), 256, 0, stream>>>(q, kbuf, cst);
    // K^T V (64x64 per head) and c^T V
    ktv_kernel<<<HEADS, 256, 0, stream>>>(kbuf, vbuf, cst, ktv, cv);
    // attn = (1/8) Q (K^T V) − 1·(c^T V)   [rank-1 log_softmax correction]
    attn_kernel<<<dim3(N_TOK / 64, HEADS), 256, 0, stream>>>(q, ktv, cv, attn);
    // Z = attn @ WO + bO
    gemm_kernel<0, 0, 0><<<dim3(16, 32), 256, 0, stream>>>(attn, WO, oWO, bO, obO, z, N_TOK, DMODEL, DMODEL, dtf);
    // h2 = LN(h + Z)
    ln_kernel<<<N_TOK, 256, 0, stream>>>(h, z, g1, be1, oLN, h2, nullptr, dtf);
    // FFN
    gemm_kernel<0, 0, 1><<<dim3(64, 32), 256, 0, stream>>>(h2, W1, oW1, b1, ob1, mid, N_TOK, DFF, DMODEL, dtf);
    gemm_kernel<0, 0, 0><<<dim3(16, 32), 256, 0, stream>>>(mid, W2, oW2, b2, ob2, rbuf, N_TOK, DMODEL, DFF, dtf);
    // h = LN(h2 + R); last layer also writes d_out in the detected dtype
    void* ob = (l == LAYERS - 1) ? d_out : nullptr;
    ln_kernel<<<N_TOK, 256, 0, stream>>>(h2, rbuf, g2, be2, oLN, h, ob, dtf);
  }
}